// Round 5
// baseline (194.114 us; speedup 1.0000x reference)
//
#include <hip/hip_runtime.h>
#include <hip/hip_bf16.h>

// Problem: B=128, S=4096, C=64.  r[b,t] = p_t . (M p_{t+1}),  p = log_softmax(logits)
// sigma-permuted class storage in LDS: c' = 4*(c&15) + (c>>4), applied to BOTH P and M
// (MFMA is invariant to a shared k-permutation). Phase-3 then reads each lane's 4
// classes {16nt+nlo} as one contiguous ds_read_b64 at c' = 4*nlo.
//
// Structure: persistent waves. 512 blocks x 4 waves, each wave owns 8 chunks of 32
// outputs (33 logits rows incl. overlap). Wave-autonomous P tile -> no barrier in the
// steady loop; chunk i+1's global loads issue before chunk i's compute (double-buffered
// registers) so ~8 KB/wave stays in flight continuously.
#define SS 4096
#define CC 64
#define PST 72            // LDS row stride in bf16 (144 B = 9 x 16 B)
#define WROWS 33
#define NITER 8
#define NBLK 512

typedef __attribute__((ext_vector_type(8))) short short8;
typedef __attribute__((ext_vector_type(4))) float floatx4;

static __device__ __forceinline__ unsigned short f2bf(float f) {
    __hip_bfloat16 h = __float2bfloat16(f);
    return *reinterpret_cast<unsigned short*>(&h);
}
static __device__ __forceinline__ float bf2f(unsigned short u) {
    __hip_bfloat16 h; *reinterpret_cast<unsigned short*>(&h) = u;
    return __bfloat162float(h);
}
static __device__ __forceinline__ float f4c(const float4& v, int k) {
    switch (k & 3) { case 0: return v.x; case 1: return v.y; case 2: return v.z; default: return v.w; }
}

// DPP cross-lane reductions (VALU pipe, no LDS traffic)
#define DPP_QX1 0xB1   // quad_perm xor1
#define DPP_QX2 0x4E   // quad_perm xor2
#define DPP_HM  0x141  // row_half_mirror (xor7 in 8)
#define DPP_RM  0x140  // row_mirror (xor15 in 16)
template<int CTRL>
static __device__ __forceinline__ float dpp_fadd(float v) {
    int p = __builtin_amdgcn_update_dpp(0, __float_as_int(v), CTRL, 0xf, 0xf, true);
    return v + __int_as_float(p);
}
template<int CTRL>
static __device__ __forceinline__ float dpp_fmax(float v) {
    int p = __builtin_amdgcn_update_dpp(0, __float_as_int(v), CTRL, 0xf, 0xf, true);
    return fmaxf(v, __int_as_float(p));
}

__global__ __launch_bounds__(256, 2) void pkl_kernel(
        const float* __restrict__ logits,
        const float* __restrict__ M,
        float* __restrict__ out) {
    __shared__ __hip_bfloat16 mt_lds[CC * PST];        // M rows, sigma cols
    __shared__ __hip_bfloat16 pt_lds[4][WROWS * PST];  // per-wave P tiles, sigma cols

    const int tid  = threadIdx.x;
    const int lane = tid & 63;
    const int w    = tid >> 6;
    const int quad = lane >> 4;   // 0..3
    const int nlo  = lane & 15;   // 0..15
    const int rq   = lane >> 2;   // softmax: row-within-group 0..15
    const int q    = lane & 3;    // softmax: quarter of row

    const float LOG2E = 1.4426950408889634f, LN2 = 0.6931471805599453f;

    // ---- one-time: stage M into LDS with sigma columns (coalesced reads) ----
    #pragma unroll
    for (int j = 0; j < 16; ++j) {
        int idx = j * 256 + tid, c = idx >> 6, d = idx & 63;
        mt_lds[c * PST + 4 * (d & 15) + (d >> 4)] = __float2bfloat16(M[idx]);
    }
    __syncthreads();   // only barrier in the kernel

    // ---- hoist M B-fragments into registers (read once, reused all 8 chunks) ----
    short8 bfrag[2][4];
    #pragma unroll
    for (int kt = 0; kt < 2; ++kt)
        #pragma unroll
        for (int nt = 0; nt < 4; ++nt)
            bfrag[kt][nt] = *reinterpret_cast<const short8*>(
                reinterpret_cast<const short*>(mt_lds) + (nt * 16 + nlo) * PST + kt * 32 + quad * 8);

    short* pw = reinterpret_cast<short*>(pt_lds[w]);
    const int gw = blockIdx.x * 4 + w;                 // 0..2047

    float4 xa[2][2][4];   // [buf][row-group][j]

    // prefetch chunk it=0
    {
        const int chunk = gw;
        const int b = chunk >> 7, s0 = (chunk & 127) * 32;
        const float* base = logits + ((size_t)b * SS + s0) * CC;
        #pragma unroll
        for (int g = 0; g < 2; ++g)
            #pragma unroll
            for (int j = 0; j < 4; ++j)
                xa[0][g][j] = *reinterpret_cast<const float4*>(
                    base + (size_t)(g * 16 + rq) * CC + (j * 4 + q) * 4);
    }

    #pragma unroll
    for (int it = 0; it < NITER; ++it) {
        const int buf = it & 1;
        const int chunk = it * 2048 + gw;
        const int b = chunk >> 7, s0 = (chunk & 127) * 32;

        // ---- prefetch chunk it+1 into the other register buffer ----
        if (it + 1 < NITER) {
            const int nc = (it + 1) * 2048 + gw;
            const int nb = nc >> 7, ns0 = (nc & 127) * 32;
            const float* nbase = logits + ((size_t)nb * SS + ns0) * CC;
            #pragma unroll
            for (int g = 0; g < 2; ++g)
                #pragma unroll
                for (int j = 0; j < 4; ++j)
                    xa[buf ^ 1][g][j] = *reinterpret_cast<const float4*>(
                        nbase + (size_t)(g * 16 + rq) * CC + (j * 4 + q) * 4);
        }

        // ---- overlap row (local row 32) load: lanes 0..3 only ----
        float4 xo[4];
        const int grow = (s0 + 32 > SS - 1) ? (SS - 1) : (s0 + 32);
        if (rq == 0) {
            const float* op = logits + ((size_t)b * SS + grow) * CC;
            #pragma unroll
            for (int j = 0; j < 4; ++j)
                xo[j] = *reinterpret_cast<const float4*>(op + (j * 4 + q) * 4);
        }

        // ---- softmax: 16 in-lane values + 2 DPP steps over the row's 4-lane quad ----
        #pragma unroll
        for (int g = 0; g < 2; ++g) {
            float mx = f4c(xa[buf][g][0], 0);
            #pragma unroll
            for (int j = 0; j < 4; ++j)
                #pragma unroll
                for (int k = 0; k < 4; ++k)
                    mx = fmaxf(mx, f4c(xa[buf][g][j], k));
            mx = dpp_fmax<DPP_QX1>(mx); mx = dpp_fmax<DPP_QX2>(mx);
            float sm = 0.f;
            #pragma unroll
            for (int j = 0; j < 4; ++j)
                #pragma unroll
                for (int k = 0; k < 4; ++k)
                    sm += exp2f((f4c(xa[buf][g][j], k) - mx) * LOG2E);
            sm = dpp_fadd<DPP_QX1>(sm); sm = dpp_fadd<DPP_QX2>(sm);
            const float lse = mx + log2f(sm) * LN2;
            short8 h0, h1;
            #pragma unroll
            for (int o = 0; o < 8; ++o) {                      // o = 4k+j, c' = 16q+o
                h0[o] = (short)f2bf(f4c(xa[buf][g][o & 3], o >> 2) - lse);
                h1[o] = (short)f2bf(f4c(xa[buf][g][(o + 8) & 3], (o + 8) >> 2) - lse);
            }
            short* pp = pw + (g * 16 + rq) * PST + 16 * q;
            *reinterpret_cast<short8*>(pp) = h0;
            *reinterpret_cast<short8*>(pp + 8) = h1;
        }
        if (rq == 0) {   // overlap row softmax (quad 0 lanes)
            float mx = f4c(xo[0], 0);
            #pragma unroll
            for (int j = 0; j < 4; ++j)
                #pragma unroll
                for (int k = 0; k < 4; ++k)
                    mx = fmaxf(mx, f4c(xo[j], k));
            mx = dpp_fmax<DPP_QX1>(mx); mx = dpp_fmax<DPP_QX2>(mx);
            float sm = 0.f;
            #pragma unroll
            for (int j = 0; j < 4; ++j)
                #pragma unroll
                for (int k = 0; k < 4; ++k)
                    sm += exp2f((f4c(xo[j], k) - mx) * LOG2E);
            sm = dpp_fadd<DPP_QX1>(sm); sm = dpp_fadd<DPP_QX2>(sm);
            const float lse = mx + log2f(sm) * LN2;
            short8 h0, h1;
            #pragma unroll
            for (int o = 0; o < 8; ++o) {
                h0[o] = (short)f2bf(f4c(xo[o & 3], o >> 2) - lse);
                h1[o] = (short)f2bf(f4c(xo[(o + 8) & 3], (o + 8) >> 2) - lse);
            }
            short* pp = pw + 32 * PST + 16 * q;
            *reinterpret_cast<short8*>(pp) = h0;
            *reinterpret_cast<short8*>(pp + 8) = h1;
        }

        // ---- MFMA: V[i][c] = sum_d P[1+i][d] * M[c][d]  (sigma-k, 16x16x32) ----
        floatx4 acc[2][4];
        #pragma unroll
        for (int mt = 0; mt < 2; ++mt)
            #pragma unroll
            for (int nt = 0; nt < 4; ++nt)
                acc[mt][nt] = (floatx4){0.f, 0.f, 0.f, 0.f};
        #pragma unroll
        for (int kt = 0; kt < 2; ++kt) {
            const int koff = kt * 32 + quad * 8;
            #pragma unroll
            for (int mt = 0; mt < 2; ++mt) {
                short8 afrag = *reinterpret_cast<const short8*>(
                    pw + (1 + mt * 16 + nlo) * PST + koff);
                #pragma unroll
                for (int nt = 0; nt < 4; ++nt)
                    acc[mt][nt] = __builtin_amdgcn_mfma_f32_16x16x32_bf16(
                        afrag, bfrag[kt][nt], acc[mt][nt], 0, 0, 0);
            }
        }

        // ---- phase 3: r[t] = dot(p_t, V[t+1]); acc[mt][nt][r] = V[1+mt*16+quad*4+r][16nt+nlo] ----
        const size_t outbase = (size_t)b * (SS - 1);
        #pragma unroll
        for (int mt = 0; mt < 2; ++mt)
            #pragma unroll
            for (int r = 0; r < 4; ++r) {
                const int lrow = mt * 16 + quad * 4 + r;       // local t, 0..31
                ushort4 pd = *reinterpret_cast<const ushort4*>(
                    reinterpret_cast<const unsigned short*>(pw) + lrow * PST + 4 * nlo);
                float s = bf2f(pd.x) * acc[mt][0][r] + bf2f(pd.y) * acc[mt][1][r]
                        + bf2f(pd.z) * acc[mt][2][r] + bf2f(pd.w) * acc[mt][3][r];
                s = dpp_fadd<DPP_QX1>(s); s = dpp_fadd<DPP_QX2>(s);
                s = dpp_fadd<DPP_HM>(s);  s = dpp_fadd<DPP_RM>(s);
                if (nlo == 0) {
                    const int t = s0 + lrow;
                    if (t <= SS - 2) out[outbase + t] = s;
                }
            }
    }
}

extern "C" void kernel_launch(void* const* d_in, const int* in_sizes, int n_in,
                              void* d_out, int out_size, void* d_ws, size_t ws_size,
                              hipStream_t stream) {
    const float* logits = (const float*)d_in[0];   // [128, 4096, 64] fp32
    const float* M      = (const float*)d_in[1];   // [64, 64] fp32
    float* out          = (float*)d_out;           // [128, 4095] fp32

    dim3 grid(NBLK), block(256);                   // persistent: 2 blocks/CU, 8 chunks/wave
    hipLaunchKernelGGL(pkl_kernel, grid, block, 0, stream, logits, M, out);
}